// Round 1
// baseline (40.186 us; speedup 1.0000x reference)
//
#include <hip/hip_runtime.h>

// Problem constants (match reference)
#define HH 512
#define WW 512
#define NB 8
constexpr int   NPIX = HH * WW;              // 262144 pixels per batch
constexpr int   FH   = (HH - 1) * (WW - 1);  // 261121 lower faces per batch
constexpr int   NF   = 2 * FH;               // 522242 faces per batch
constexpr float EPS       = 0.04f;
constexpr float DEPTH_MIN = 0.1f;
constexpr float EDGE_MAX  = 0.1f;

// Kernel 1: per-pixel unprojection.
//   v = c2w_ext · [ c2w_int · (x*z, y*z, z), 1 ]
//   a = attributes with edge extension on last row / last col / corner
__global__ void __launch_bounds__(256)
unproject_kernel(const float* __restrict__ attr_d,
                 const float* __restrict__ c2w_int,
                 const float* __restrict__ c2w_ext,
                 float* __restrict__ out_v,
                 float* __restrict__ out_a) {
    int idx = blockIdx.x * blockDim.x + threadIdx.x;
    if (idx >= NB * NPIX) return;
    int b   = idx / NPIX;
    int pix = idx - b * NPIX;
    int h   = pix / WW;
    int w   = pix - h * WW;

    const float* base = attr_d + (size_t)b * 4 * NPIX;  // planar (C,H,W)
    float z = base[3 * NPIX + pix];

    // attributes channels 0..2, with boundary extension (all reads use
    // original values — the three jnp .at[].add regions are disjoint)
    float a[3];
#pragma unroll
    for (int c = 0; c < 3; ++c) {
        const float* pc = base + c * NPIX;
        float av = pc[pix];
        if (h == HH - 1 && w < WW - 1) {
            av = av + (av - pc[pix - WW]) * EPS;            // last row (exc. corner)
        } else if (w == WW - 1 && h < HH - 1) {
            av = av + (av - pc[pix - 1]) * EPS;             // last col (exc. corner)
        } else if (h == HH - 1 && w == WW - 1) {
            av = av + (av - pc[pix - WW - 1]) * EPS;        // corner (diag neighbor)
        }
        a[c] = av;
    }

    // _make_lin: exactly i+0.5, last element += 0.04 (same IEEE add order)
    float x = (w == WW - 1) ? ((float)WW - 0.5f + EPS) : ((float)w + 0.5f);
    float y = (h == HH - 1) ? ((float)HH - 0.5f + EPS) : ((float)h + 0.5f);

    const float* K = c2w_int + b * 9;   // 3x3
    const float* E = c2w_ext + b * 12;  // 3x4
    float p0 = x * z, p1 = y * z, p2 = z;
    float vi0 = K[0] * p0 + K[1] * p1 + K[2] * p2;
    float vi1 = K[3] * p0 + K[4] * p1 + K[5] * p2;
    float vi2 = K[6] * p0 + K[7] * p1 + K[8] * p2;
    float v0 = E[0] * vi0 + E[1] * vi1 + E[2]  * vi2 + E[3];
    float v1 = E[4] * vi0 + E[5] * vi1 + E[6]  * vi2 + E[7];
    float v2 = E[8] * vi0 + E[9] * vi1 + E[10] * vi2 + E[11];

    size_t vo = (size_t)idx * 3;
    out_v[vo]     = v0;
    out_v[vo + 1] = v1;
    out_v[vo + 2] = v2;
    out_a[vo]     = a[0];
    out_a[vo + 1] = a[1];
    out_a[vo + 2] = a[2];
}

__device__ __forceinline__ float edge_len3(float ax, float ay, float az,
                                           float bx, float by, float bz) {
    float dx = ax - bx, dy = ay - by, dz = az - bz;
    return sqrtf(dx * dx + dy * dy + dz * dz);
}

// Kernel 2: one thread per QUAD -> both lower and upper triangle.
// lower face q: (p, p+W, p+W+1); upper face FH+q: (p, p+W+1, p+1)
// edge i = v_i - v_{i+1 mod 3}; mask = all(depth > 0.1) & all(len < 0.1)
__global__ void __launch_bounds__(256)
faces_kernel(const float* __restrict__ attr_d,
             const float* __restrict__ v_buf,
             float* __restrict__ out_e,
             float* __restrict__ out_m) {
    int idx = blockIdx.x * blockDim.x + threadIdx.x;
    if (idx >= NB * FH) return;
    int b = idx / FH;
    int q = idx - b * FH;
    int y = q / (WW - 1);
    int x = q - y * (WW - 1);
    int p = y * WW + x;

    const float* zb = attr_d + ((size_t)b * 4 + 3) * NPIX;
    float d00 = zb[p];
    float d01 = zb[p + 1];
    float d10 = zb[p + WW];
    float d11 = zb[p + WW + 1];

    const float* vb = v_buf + (size_t)b * NPIX * 3;
    const float* q00 = vb + (size_t)p * 3;
    const float* q01 = vb + (size_t)(p + 1) * 3;
    const float* q10 = vb + (size_t)(p + WW) * 3;
    const float* q11 = vb + (size_t)(p + WW + 1) * 3;
    float v00x = q00[0], v00y = q00[1], v00z = q00[2];
    float v01x = q01[0], v01y = q01[1], v01z = q01[2];
    float v10x = q10[0], v10y = q10[1], v10z = q10[2];
    float v11x = q11[0], v11y = q11[1], v11z = q11[2];

    // 5 distinct edge lengths serve both faces
    float l_a = edge_len3(v00x, v00y, v00z, v10x, v10y, v10z);  // lower e0
    float l_b = edge_len3(v10x, v10y, v10z, v11x, v11y, v11z);  // lower e1
    float l_c = edge_len3(v11x, v11y, v11z, v00x, v00y, v00z);  // lower e2 / upper e0 (sign-symmetric)
    float l_d = edge_len3(v11x, v11y, v11z, v01x, v01y, v01z);  // upper e1
    float l_e = edge_len3(v01x, v01y, v01z, v00x, v00y, v00z);  // upper e2

    bool m_low = (d00 > DEPTH_MIN) & (d10 > DEPTH_MIN) & (d11 > DEPTH_MIN) &
                 (l_a < EDGE_MAX) & (l_b < EDGE_MAX) & (l_c < EDGE_MAX);
    bool m_up  = (d00 > DEPTH_MIN) & (d11 > DEPTH_MIN) & (d01 > DEPTH_MIN) &
                 (l_c < EDGE_MAX) & (l_d < EDGE_MAX) & (l_e < EDGE_MAX);

    size_t e_low = ((size_t)b * NF + q) * 3;
    size_t e_up  = ((size_t)b * NF + FH + q) * 3;
    out_e[e_low]     = l_a;
    out_e[e_low + 1] = l_b;
    out_e[e_low + 2] = l_c;
    out_e[e_up]      = l_c;
    out_e[e_up + 1]  = l_d;
    out_e[e_up + 2]  = l_e;

    out_m[(size_t)b * NF + q]      = m_low ? 1.0f : 0.0f;
    out_m[(size_t)b * NF + FH + q] = m_up ? 1.0f : 0.0f;
}

extern "C" void kernel_launch(void* const* d_in, const int* in_sizes, int n_in,
                              void* d_out, int out_size, void* d_ws, size_t ws_size,
                              hipStream_t stream) {
    const float* attr_d  = (const float*)d_in[0];
    const float* c2w_int = (const float*)d_in[1];
    const float* c2w_ext = (const float*)d_in[2];

    float* out   = (float*)d_out;
    float* out_v = out;                                  // B*N*3 = 6291456
    float* out_a = out + (size_t)NB * NPIX * 3;          // B*N*3 = 6291456
    float* out_e = out + (size_t)2 * NB * NPIX * 3;      // B*F*3 = 12533808
    float* out_m = out_e + (size_t)NB * NF * 3;          // B*F   = 4177936

    int t1 = NB * NPIX;
    unproject_kernel<<<(t1 + 255) / 256, 256, 0, stream>>>(attr_d, c2w_int, c2w_ext,
                                                           out_v, out_a);
    int t2 = NB * FH;
    faces_kernel<<<(t2 + 255) / 256, 256, 0, stream>>>(attr_d, out_v, out_e, out_m);
}